// Round 6
// baseline (436.507 us; speedup 1.0000x reference)
//
#include <hip/hip_runtime.h>

#define W 1024
#define H 1024
#define PADX 16                       // col zero-pad each side
#define PADY 8                        // row zero-pad each side
#define XS 1056                       // padded row stride (floats)
#define YS 1040                       // padded row count
#define FR ((size_t)XS * (size_t)YS)  // floats per padded buffer
#define NPIX (H * W)
#define TROWS 32                      // tile rows per block
#define TCOLS 64                      // tile cols per block
#define LRN 42                        // local rows: gr in [r0-5, r0+37)
#define LCW 88                        // local row stride (floats): gc in [c0-12, c0+76)
#define NSLOT 400                     // 40 rows x 10 col-groups (8 px each)
#define NB 512

__device__ __forceinline__ float frcp_(float v) { return __builtin_amdgcn_rcpf(v); }
__device__ __forceinline__ float sigm_(float v) { return frcp_(1.0f + __expf(-v)); }
__device__ __forceinline__ float tanh_(float v) {
    return 1.0f - 2.0f * frcp_(1.0f + __expf(2.0f * v));
}

// Pads the 20 input frames into ws[0..20FR) (interior copy, zero halo) and
// zeroes the 6 state buffers ws[20FR..26FR).
__global__ __launch_bounds__(256) void init_pad(const float* __restrict__ data,
                                                float* __restrict__ ws) {
    const int R4 = XS / 4;                 // 264 float4 per padded row
    const size_t n4_fr  = 20 * (FR / 4);
    const size_t n4_tot = 26 * (FR / 4);
    size_t i = (size_t)blockIdx.x * blockDim.x + threadIdx.x;
    const size_t stride = (size_t)gridDim.x * blockDim.x;
    float4* w4 = (float4*)ws;
    for (; i < n4_tot; i += stride) {
        float4 v = make_float4(0.f, 0.f, 0.f, 0.f);
        if (i < n4_fr) {
            size_t f = i / (size_t)(YS * R4);
            int rem = (int)(i - f * (size_t)(YS * R4));
            int pr  = rem / R4;            // padded row
            int k4  = rem - pr * R4;       // float4 index in row
            if (pr >= PADY && pr < PADY + H &&
                k4 >= PADX / 4 && k4 < PADX / 4 + W / 4) {
                v = *(const float4*)(data + f * (size_t)NPIX +
                                     (size_t)(pr - PADY) * W + (4 * k4 - PADX));
            }
        }
        w4[i] = v;
    }
}

// 3 rows x (8-wide) conv of one channel into acc[4][8].
// p points at the slot's top-left (row gr-1, col gc0); stride = row stride.
__device__ __forceinline__ void conv3x8(const float* __restrict__ p, int stride,
                                        const float* __restrict__ wg, int wofs,
                                        float acc[4][8]) {
#pragma unroll
    for (int dy = 0; dy < 3; ++dy) {
        const float4 a = *(const float4*)p;
        const float4 b = *(const float4*)(p + 4);
        const float in10[10] = {p[-1], a.x, a.y, a.z, a.w,
                                b.x, b.y, b.z, b.w, p[8]};
#pragma unroll
        for (int co = 0; co < 4; ++co) {
            const float w0 = wg[co * 18 + wofs + dy * 3 + 0];
            const float w1 = wg[co * 18 + wofs + dy * 3 + 1];
            const float w2 = wg[co * 18 + wofs + dy * 3 + 2];
#pragma unroll
            for (int e = 0; e < 8; ++e)
                acc[co][e] += w0 * in10[e] + w1 * in10[e + 1] + w2 * in10[e + 2];
        }
        p += stride;
    }
}

// 5 fused conv-LSTM steps. Grid 512 (32 row-tiles x 16 col-tiles of 32x64 px),
// 512 threads. h tile in LDS (42 rows x 88); c entirely in registers.
// Thread t < 400 owns one fixed 8-px slot (row lr=1+t/10, col-group jj=t%10);
// step i computes rows lr in [i, 42-i). Fresh-region shrink matches stencil
// pollution, so the 32x64 interior is exact after step 5. All local arrays
// statically indexed -> no scratch.
__global__ __launch_bounds__(NB, 4) void fused5(
    const float* __restrict__ xbase, size_t xstep,
    const float* __restrict__ hin, const float* __restrict__ cin,
    float* __restrict__ hout, float* __restrict__ cout_,
    const float* __restrict__ wg, const float* __restrict__ bg,
    float* __restrict__ dout, int zero_init)
{
    __shared__ float hT[LRN * LCW];
    const int tid = threadIdx.x;
    const int c0 = (blockIdx.x & 15) * TCOLS;
    const int r0 = (blockIdx.x >> 4) * TROWS;

    const bool has = tid < NSLOT;
    const int q   = tid / 10;             // slot row index 0..39
    const int jj  = tid - q * 10;         // col group 0..9
    const int lr  = 1 + q;                // local row 1..40
    const int lc  = 4 + 8 * jj;           // local col 4..76
    const int gr  = r0 - 5 + lr;          // global row of slot
    const int gc0 = c0 - 12 + lc;         // global col of slot (multiple of 8)
    const size_t gofs = (size_t)(gr + PADY) * XS + (gc0 + PADX);
    const bool inimg = ((unsigned)gr < (unsigned)H) && ((unsigned)gc0 < (unsigned)W);

    // ---- initial LDS h tile (42 x 22 float4) ----
    // local row r holds global row gr=r0-5+r -> padded row gr+PADY = r0+3+r
    for (int idx = tid; idx < LRN * (LCW / 4); idx += NB) {
        const int r = idx / (LCW / 4);
        const int k = idx - r * (LCW / 4);
        float4 v = make_float4(0.f, 0.f, 0.f, 0.f);
        if (!zero_init)
            v = *(const float4*)(hin + (size_t)(r0 + 3 + r) * XS +
                                 (c0 - 12 + 4 * k + PADX));
        *(float4*)(hT + r * LCW + 4 * k) = v;
    }

    // ---- c state in registers ----
    float cc[8];
    if (has && !zero_init) {
        const float4 a = *(const float4*)(cin + gofs);
        const float4 b = *(const float4*)(cin + gofs + 4);
        cc[0] = a.x; cc[1] = a.y; cc[2] = a.z; cc[3] = a.w;
        cc[4] = b.x; cc[5] = b.y; cc[6] = b.z; cc[7] = b.w;
    } else {
#pragma unroll
        for (int e = 0; e < 8; ++e) cc[e] = 0.f;
    }
    __syncthreads();

    float hh[8];
#pragma unroll
    for (int e = 0; e < 8; ++e) hh[e] = 0.f;

#pragma unroll
    for (int i = 1; i <= 5; ++i) {
        const bool act = has && (lr >= i) && (lr < LRN - i);
        if (act) {
            float acc[4][8];
#pragma unroll
            for (int co = 0; co < 4; ++co) {
                const float bb = bg[co];
#pragma unroll
                for (int e = 0; e < 8; ++e) acc[co][e] = bb;
            }
            conv3x8(xbase + (size_t)(i - 1) * xstep + gofs - XS, XS, wg, 0, acc);
            conv3x8(hT + (lr - 1) * LCW + lc, LCW, wg, 9, acc);
#pragma unroll
            for (int e = 0; e < 8; ++e) {
                const float gi = sigm_(acc[0][e]);
                const float gf = sigm_(acc[1][e]);
                const float go = sigm_(acc[2][e]);
                const float gg = tanh_(acc[3][e]);
                const float cn = gf * cc[e] + gi * gg;
                cc[e] = cn;
                hh[e] = inimg ? (go * tanh_(cn)) : 0.f;  // SAME zero-padding
            }
        }
        __syncthreads();   // all reads of h_{i-1} complete
        if (act) {
            *(float4*)(hT + lr * LCW + lc)     = make_float4(hh[0], hh[1], hh[2], hh[3]);
            *(float4*)(hT + lr * LCW + lc + 4) = make_float4(hh[4], hh[5], hh[6], hh[7]);
        }
        __syncthreads();   // h_i visible
    }

    // ---- interior write-out: rows lr in [5,37) (= tile interior), jj 1..8 ----
    if (has && lr >= 5 && lr < 5 + TROWS && jj >= 1 && jj <= 8) {
        if (dout) {
            const size_t o = (size_t)gr * W + gc0;
            *(float4*)(dout + o)     = make_float4(hh[0], hh[1], hh[2], hh[3]);
            *(float4*)(dout + o + 4) = make_float4(hh[4], hh[5], hh[6], hh[7]);
        } else {
            *(float4*)(hout + gofs)      = make_float4(hh[0], hh[1], hh[2], hh[3]);
            *(float4*)(hout + gofs + 4)  = make_float4(hh[4], hh[5], hh[6], hh[7]);
            *(float4*)(cout_ + gofs)     = make_float4(cc[0], cc[1], cc[2], cc[3]);
            *(float4*)(cout_ + gofs + 4) = make_float4(cc[4], cc[5], cc[6], cc[7]);
        }
    }
}

extern "C" void kernel_launch(void* const* d_in, const int* in_sizes, int n_in,
                              void* d_out, int out_size, void* d_ws, size_t ws_size,
                              hipStream_t stream) {
    const float* data  = (const float*)d_in[0];  // [20,1,1,1024,1024]
    const float* enc_w = (const float*)d_in[1];  // [4,2,3,3]
    const float* enc_b = (const float*)d_in[2];  // [4]
    const float* dec_w = (const float*)d_in[3];
    const float* dec_b = (const float*)d_in[4];
    // d_in[5..7] = epoch(0), T_en(20), T_de(20): constant device scalars;
    // loop counts hardcoded (host can't read device memory under capture).

    float* ws   = (float*)d_ws;
    float* xpad = ws;                 // 20 padded frames
    float* hE0  = ws + 20 * FR;
    float* hE1  = ws + 21 * FR;
    float* cE0  = ws + 22 * FR;
    float* cE1  = ws + 23 * FR;
    float* hX   = ws + 24 * FR;
    float* cX   = ws + 25 * FR;
    float* dout = (float*)d_out;
    // ws use: 26*FR*4 B ~= 114 MB

    init_pad<<<2048, 256, 0, stream>>>(data, ws);

    dim3 blk(NB), grd(512);
    // encoder: 4 launches x 5 steps; state ping-pongs (hE1,cE1)<->(hE0,cE0)
    fused5<<<grd, blk, 0, stream>>>(xpad,           FR, nullptr, nullptr, hE1, cE1,
                                    enc_w, enc_b, nullptr, 1);
    fused5<<<grd, blk, 0, stream>>>(xpad +  5 * FR, FR, hE1, cE1, hE0, cE0,
                                    enc_w, enc_b, nullptr, 0);
    fused5<<<grd, blk, 0, stream>>>(xpad + 10 * FR, FR, hE0, cE0, hE1, cE1,
                                    enc_w, enc_b, nullptr, 0);
    fused5<<<grd, blk, 0, stream>>>(xpad + 15 * FR, FR, hE1, cE1, hE0, cE0,
                                    enc_w, enc_b, nullptr, 0);
    // final encoder h in hE0 (constant decoder input; zero halo ring = SAME pad)
    fused5<<<grd, blk, 0, stream>>>(hE0, 0, nullptr, nullptr, hE1, cE1,
                                    dec_w, dec_b, nullptr, 1);
    fused5<<<grd, blk, 0, stream>>>(hE0, 0, hE1, cE1, hX,  cX,
                                    dec_w, dec_b, nullptr, 0);
    fused5<<<grd, blk, 0, stream>>>(hE0, 0, hX,  cX,  hE1, cE1,
                                    dec_w, dec_b, nullptr, 0);
    fused5<<<grd, blk, 0, stream>>>(hE0, 0, hE1, cE1, nullptr, nullptr,
                                    dec_w, dec_b, dout, 0);
}

// Round 7
// 427.161 us; speedup vs baseline: 1.0219x; 1.0219x over previous
//
#include <hip/hip_runtime.h>

#define W 1024
#define H 1024
#define PADX 16                       // col zero-pad each side
#define PADY 8                        // row zero-pad each side
#define XS 1056                       // padded row stride (floats)
#define YS 1040                       // padded row count
#define FR ((size_t)XS * (size_t)YS)  // floats per padded buffer
#define NPIX (H * W)
#define TROWS 32                      // tile rows per block
#define TCOLS 64                      // tile cols per block
#define LRN 48                        // local rows: gr in [r0-8, r0+40)
#define LCV 96                        // valid local cols: gc in [c0-16, c0+80)
#define LCW 100                       // LDS row stride (pad 4 to stagger banks)
#define NSLOT 460                     // 46 rows x 10 col-groups (8 px each)
#define NB 512

__device__ __forceinline__ float frcp_(float v) { return __builtin_amdgcn_rcpf(v); }
__device__ __forceinline__ float sigm_(float v) { return frcp_(1.0f + __expf(-v)); }
__device__ __forceinline__ float tanh_(float v) {
    return 1.0f - 2.0f * frcp_(1.0f + __expf(2.0f * v));
}

// Pads the 20 input frames into ws[0..20FR) (interior copy, zero halo) and
// zeroes the 6 state buffers ws[20FR..26FR).
__global__ __launch_bounds__(256) void init_pad(const float* __restrict__ data,
                                                float* __restrict__ ws) {
    const int R4 = XS / 4;                 // 264 float4 per padded row
    const size_t n4_fr  = 20 * (FR / 4);
    const size_t n4_tot = 26 * (FR / 4);
    size_t i = (size_t)blockIdx.x * blockDim.x + threadIdx.x;
    const size_t stride = (size_t)gridDim.x * blockDim.x;
    float4* w4 = (float4*)ws;
    for (; i < n4_tot; i += stride) {
        float4 v = make_float4(0.f, 0.f, 0.f, 0.f);
        if (i < n4_fr) {
            size_t f = i / (size_t)(YS * R4);
            int rem = (int)(i - f * (size_t)(YS * R4));
            int pr  = rem / R4;            // padded row
            int k4  = rem - pr * R4;       // float4 index in row
            if (pr >= PADY && pr < PADY + H &&
                k4 >= PADX / 4 && k4 < PADX / 4 + W / 4) {
                v = *(const float4*)(data + f * (size_t)NPIX +
                                     (size_t)(pr - PADY) * W + (4 * k4 - PADX));
            }
        }
        w4[i] = v;
    }
}

// 3 rows x (8-wide) conv of one channel into acc[4][8].
// p points at the slot's top-left (row gr-1, col gc0); stride = row stride.
__device__ __forceinline__ void conv3x8(const float* __restrict__ p, int stride,
                                        const float* __restrict__ wg, int wofs,
                                        float acc[4][8]) {
#pragma unroll
    for (int dy = 0; dy < 3; ++dy) {
        const float4 a = *(const float4*)p;
        const float4 b = *(const float4*)(p + 4);
        const float in10[10] = {p[-1], a.x, a.y, a.z, a.w,
                                b.x, b.y, b.z, b.w, p[8]};
#pragma unroll
        for (int co = 0; co < 4; ++co) {
            const float w0 = wg[co * 18 + wofs + dy * 3 + 0];
            const float w1 = wg[co * 18 + wofs + dy * 3 + 1];
            const float w2 = wg[co * 18 + wofs + dy * 3 + 2];
#pragma unroll
            for (int e = 0; e < 8; ++e)
                acc[co][e] += w0 * in10[e] + w1 * in10[e + 1] + w2 * in10[e + 2];
        }
        p += stride;
    }
}

// NSTEPS fused conv-LSTM steps. Grid 512 (32 row-tiles x 16 col-tiles, 32x64
// interior each), 512 threads. h tile in LDS (48 rows x 96 valid cols, stride
// 100); c in registers. Thread t < 460 owns one fixed 8-px slot (row lr=1+t/10,
// col-group jj=t%10, cols gc0=c0-8+8jj); step i computes rows lr in [i,48-i).
// Stale-boundary pollution (1 px/step after one grace step) reaches cols
// [<=c0-2] and [>=c0+65] and never touches the 32x64 interior for NSTEPS<=8.
template<int NSTEPS>
__global__ __launch_bounds__(NB, 4) void fusedN(
    const float* __restrict__ xbase, size_t xstep,
    const float* __restrict__ hin, const float* __restrict__ cin,
    float* __restrict__ hout, float* __restrict__ cout_,
    const float* __restrict__ wg, const float* __restrict__ bg,
    float* __restrict__ dout, int zero_init)
{
    __shared__ float hT[LRN * LCW];
    const int tid = threadIdx.x;
    const int c0 = (blockIdx.x & 15) * TCOLS;
    const int r0 = (blockIdx.x >> 4) * TROWS;

    const bool has = tid < NSLOT;
    const int q   = tid / 10;             // slot row index 0..45
    const int jj  = tid - q * 10;         // col group 0..9
    const int lr  = 1 + q;                // local row 1..46
    const int lc  = 8 + 8 * jj;           // local col 8..80
    const int gr  = r0 - 8 + lr;          // global row of slot
    const int gc0 = c0 - 8 + 8 * jj;      // global col of slot (multiple of 8)
    const size_t gofs = (size_t)(gr + PADY) * XS + (gc0 + PADX);
    const bool inimg = ((unsigned)gr < (unsigned)H) && ((unsigned)gc0 < (unsigned)W);

    // ---- initial LDS h tile: 48 rows x 24 float4 (96 valid cols) ----
    // local row r holds global row r0-8+r -> padded row r0+r;
    // local col 4k holds global col c0-16+4k -> padded col c0+4k
    for (int idx = tid; idx < LRN * (LCV / 4); idx += NB) {
        const int r = idx / (LCV / 4);
        const int k = idx - r * (LCV / 4);
        float4 v = make_float4(0.f, 0.f, 0.f, 0.f);
        if (!zero_init)
            v = *(const float4*)(hin + (size_t)(r0 + r) * XS + (c0 + 4 * k));
        *(float4*)(hT + r * LCW + 4 * k) = v;
    }

    // ---- c state in registers ----
    float cc[8];
    if (has && !zero_init) {
        const float4 a = *(const float4*)(cin + gofs);
        const float4 b = *(const float4*)(cin + gofs + 4);
        cc[0] = a.x; cc[1] = a.y; cc[2] = a.z; cc[3] = a.w;
        cc[4] = b.x; cc[5] = b.y; cc[6] = b.z; cc[7] = b.w;
    } else {
#pragma unroll
        for (int e = 0; e < 8; ++e) cc[e] = 0.f;
    }
    __syncthreads();

    float hh[8];
#pragma unroll
    for (int e = 0; e < 8; ++e) hh[e] = 0.f;

#pragma unroll
    for (int i = 1; i <= NSTEPS; ++i) {
        const bool act = has && (lr >= i) && (lr < LRN - i);
        if (act) {
            float acc[4][8];
#pragma unroll
            for (int co = 0; co < 4; ++co) {
                const float bb = bg[co];
#pragma unroll
                for (int e = 0; e < 8; ++e) acc[co][e] = bb;
            }
            conv3x8(xbase + (size_t)(i - 1) * xstep + gofs - XS, XS, wg, 0, acc);
            conv3x8(hT + (lr - 1) * LCW + lc, LCW, wg, 9, acc);
#pragma unroll
            for (int e = 0; e < 8; ++e) {
                const float gi = sigm_(acc[0][e]);
                const float gf = sigm_(acc[1][e]);
                const float go = sigm_(acc[2][e]);
                const float gg = tanh_(acc[3][e]);
                const float cn = gf * cc[e] + gi * gg;
                cc[e] = cn;
                hh[e] = inimg ? (go * tanh_(cn)) : 0.f;  // SAME zero-padding
            }
        }
        __syncthreads();   // all reads of h_{i-1} complete
        if (act) {
            *(float4*)(hT + lr * LCW + lc)     = make_float4(hh[0], hh[1], hh[2], hh[3]);
            *(float4*)(hT + lr * LCW + lc + 4) = make_float4(hh[4], hh[5], hh[6], hh[7]);
        }
        __syncthreads();   // h_i visible
    }

    // ---- interior write-out: rows lr in [8,40), col groups jj in [1,8] ----
    if (has && lr >= 8 && lr < 8 + TROWS && jj >= 1 && jj <= 8) {
        if (dout) {
            const size_t o = (size_t)gr * W + gc0;
            *(float4*)(dout + o)     = make_float4(hh[0], hh[1], hh[2], hh[3]);
            *(float4*)(dout + o + 4) = make_float4(hh[4], hh[5], hh[6], hh[7]);
        } else {
            *(float4*)(hout + gofs)      = make_float4(hh[0], hh[1], hh[2], hh[3]);
            *(float4*)(hout + gofs + 4)  = make_float4(hh[4], hh[5], hh[6], hh[7]);
            *(float4*)(cout_ + gofs)     = make_float4(cc[0], cc[1], cc[2], cc[3]);
            *(float4*)(cout_ + gofs + 4) = make_float4(cc[4], cc[5], cc[6], cc[7]);
        }
    }
}

extern "C" void kernel_launch(void* const* d_in, const int* in_sizes, int n_in,
                              void* d_out, int out_size, void* d_ws, size_t ws_size,
                              hipStream_t stream) {
    const float* data  = (const float*)d_in[0];  // [20,1,1,1024,1024]
    const float* enc_w = (const float*)d_in[1];  // [4,2,3,3]
    const float* enc_b = (const float*)d_in[2];  // [4]
    const float* dec_w = (const float*)d_in[3];
    const float* dec_b = (const float*)d_in[4];
    // d_in[5..7] = epoch(0), T_en(20), T_de(20): constant device scalars;
    // loop counts hardcoded (host can't read device memory under capture).

    float* ws   = (float*)d_ws;
    float* xpad = ws;                 // 20 padded frames
    float* hE0  = ws + 20 * FR;
    float* hE1  = ws + 21 * FR;
    float* cE0  = ws + 22 * FR;
    float* cE1  = ws + 23 * FR;
    float* hX   = ws + 24 * FR;
    float* cX   = ws + 25 * FR;
    float* dout = (float*)d_out;
    // ws use: 26*FR*4 B ~= 114 MB

    init_pad<<<2048, 256, 0, stream>>>(data, ws);

    dim3 blk(NB), grd(512);
    // encoder: steps 0-7, 8-15, 16-19
    fusedN<8><<<grd, blk, 0, stream>>>(xpad,           FR, nullptr, nullptr,
                                       hE1, cE1, enc_w, enc_b, nullptr, 1);
    fusedN<8><<<grd, blk, 0, stream>>>(xpad +  8 * FR, FR, hE1, cE1,
                                       hE0, cE0, enc_w, enc_b, nullptr, 0);
    fusedN<4><<<grd, blk, 0, stream>>>(xpad + 16 * FR, FR, hE0, cE0,
                                       hE1, cE1, enc_w, enc_b, nullptr, 0);
    // final encoder h in hE1 (constant decoder input; zero halo ring = SAME pad)
    fusedN<8><<<grd, blk, 0, stream>>>(hE1, 0, nullptr, nullptr,
                                       hE0, cE0, dec_w, dec_b, nullptr, 1);
    fusedN<8><<<grd, blk, 0, stream>>>(hE1, 0, hE0, cE0,
                                       hX,  cX,  dec_w, dec_b, nullptr, 0);
    fusedN<4><<<grd, blk, 0, stream>>>(hE1, 0, hX,  cX,
                                       nullptr, nullptr, dec_w, dec_b, dout, 0);
}

// Round 8
// 377.766 us; speedup vs baseline: 1.1555x; 1.1308x over previous
//
#include <hip/hip_runtime.h>

#define W 1024
#define H 1024
#define PADX 16                       // col zero-pad each side
#define PADY 8                        // row zero-pad each side
#define XS 1056                       // padded row stride (floats)
#define YS 1040                       // padded row count
#define FR ((size_t)XS * (size_t)YS)  // floats per padded buffer
#define NPIX (H * W)
#define TROWS 32                      // tile rows per block
#define TCOLS 64                      // tile cols per block
#define LRN 48                        // local rows: gr in [r0-8, r0+40)
#define LCV 96                        // valid local cols: gc in [c0-16, c0+80)
#define LCW 100                       // LDS row stride (pad 4 to stagger banks)
#define NSLOT 460                     // 46 rows x 10 col-groups (8 px each)
#define NB 512

typedef float v2f __attribute__((ext_vector_type(2)));

__device__ __forceinline__ float frcp_(float v) { return __builtin_amdgcn_rcpf(v); }
__device__ __forceinline__ float sigm_(float v) { return frcp_(1.0f + __expf(-v)); }
__device__ __forceinline__ float tanh_(float v) {
    return 1.0f - 2.0f * frcp_(1.0f + __expf(2.0f * v));
}

// Pads the 20 input frames into ws[0..20FR) (interior copy, zero halo) and
// zeroes the 6 state buffers ws[20FR..26FR).
__global__ __launch_bounds__(256) void init_pad(const float* __restrict__ data,
                                                float* __restrict__ ws) {
    const int R4 = XS / 4;                 // 264 float4 per padded row
    const size_t n4_fr  = 20 * (FR / 4);
    const size_t n4_tot = 26 * (FR / 4);
    size_t i = (size_t)blockIdx.x * blockDim.x + threadIdx.x;
    const size_t stride = (size_t)gridDim.x * blockDim.x;
    float4* w4 = (float4*)ws;
    for (; i < n4_tot; i += stride) {
        float4 v = make_float4(0.f, 0.f, 0.f, 0.f);
        if (i < n4_fr) {
            size_t f = i / (size_t)(YS * R4);
            int rem = (int)(i - f * (size_t)(YS * R4));
            int pr  = rem / R4;            // padded row
            int k4  = rem - pr * R4;       // float4 index in row
            if (pr >= PADY && pr < PADY + H &&
                k4 >= PADX / 4 && k4 < PADX / 4 + W / 4) {
                v = *(const float4*)(data + f * (size_t)NPIX +
                                     (size_t)(pr - PADY) * W + (4 * k4 - PADX));
            }
        }
        w4[i] = v;
    }
}

// 3 rows x (8-wide) conv of one channel into acc[4][4] (pairs of outputs).
// p points at the slot's top-left (row gr-1, col gc0); stride = row stride.
// Output pair P[p]=(e=2p, e=2p+1): w0 tap uses O[p]=(col 2p-1, col 2p),
// w1 uses E[p]=(col 2p, col 2p+1), w2 uses O[p+1]. Pair vectors are built
// once per row/channel and shared across the 4 gates -> v_pk_fma_f32.
__device__ __forceinline__ void conv3x8_pk(const float* __restrict__ p, int stride,
                                           const float* __restrict__ wg, int wofs,
                                           v2f acc[4][4]) {
#pragma unroll
    for (int dy = 0; dy < 3; ++dy) {
        const float4 A  = *(const float4*)p;
        const float4 Bq = *(const float4*)(p + 4);
        const float lm = p[-1], rp = p[8];
        const v2f E0 = {A.x, A.y},  E1 = {A.z, A.w};
        const v2f E2 = {Bq.x, Bq.y}, E3 = {Bq.z, Bq.w};
        const v2f O0 = {lm, A.x},   O1 = {A.y, A.z};
        const v2f O2 = {A.w, Bq.x}, O3 = {Bq.y, Bq.z}, O4 = {Bq.w, rp};
#pragma unroll
        for (int co = 0; co < 4; ++co) {
            const float w0 = wg[co * 18 + wofs + dy * 3 + 0];
            const float w1 = wg[co * 18 + wofs + dy * 3 + 1];
            const float w2 = wg[co * 18 + wofs + dy * 3 + 2];
            const v2f W0 = {w0, w0}, W1 = {w1, w1}, W2 = {w2, w2};
            acc[co][0] += W0 * O0 + W1 * E0 + W2 * O1;
            acc[co][1] += W0 * O1 + W1 * E1 + W2 * O2;
            acc[co][2] += W0 * O2 + W1 * E2 + W2 * O3;
            acc[co][3] += W0 * O3 + W1 * E3 + W2 * O4;
        }
        p += stride;
    }
}

// NSTEPS fused conv-LSTM steps. Grid 512 (32 row-tiles x 16 col-tiles, 32x64
// interior each), 512 threads. h tile double-buffered in LDS (2 x 48 rows x
// stride 100, single barrier/step); c in registers. Thread t < 460 owns one
// fixed 8-px slot; step i computes rows lr in [i,48-i). Stale-boundary
// pollution (1 px/step after a grace step) never reaches the 32x64 interior
// for NSTEPS<=8. XCONST: x-channel conv + bias hoisted out of the step loop
// (decoder: constant input).
template<int NSTEPS, bool XCONST>
__global__ __launch_bounds__(NB, 4) void fusedN(
    const float* __restrict__ xbase, size_t xstep,
    const float* __restrict__ hin, const float* __restrict__ cin,
    float* __restrict__ hout, float* __restrict__ cout_,
    const float* __restrict__ wg, const float* __restrict__ bg,
    float* __restrict__ dout, int zero_init)
{
    __shared__ float hT[2][LRN * LCW];
    const int tid = threadIdx.x;
    const int c0 = (blockIdx.x & 15) * TCOLS;
    const int r0 = (blockIdx.x >> 4) * TROWS;

    const bool has = tid < NSLOT;
    const int q   = tid / 10;             // slot row index 0..45
    const int jj  = tid - q * 10;         // col group 0..9
    const int lr  = 1 + q;                // local row 1..46
    const int lc  = 8 + 8 * jj;           // local col 8..80
    const int gr  = r0 - 8 + lr;          // global row of slot
    const int gc0 = c0 - 8 + 8 * jj;      // global col of slot (multiple of 8)
    const size_t gofs = (size_t)(gr + PADY) * XS + (gc0 + PADX);
    const bool inimg = ((unsigned)gr < (unsigned)H) && ((unsigned)gc0 < (unsigned)W);

    // ---- initial LDS h tile into buf0 (buf1 zeroed for hygiene) ----
    // local row r holds global row r0-8+r -> padded row r0+r;
    // local col 4k holds global col c0-16+4k -> padded col c0+4k
    for (int idx = tid; idx < LRN * (LCV / 4); idx += NB) {
        const int r = idx / (LCV / 4);
        const int k = idx - r * (LCV / 4);
        float4 v = make_float4(0.f, 0.f, 0.f, 0.f);
        if (!zero_init)
            v = *(const float4*)(hin + (size_t)(r0 + r) * XS + (c0 + 4 * k));
        *(float4*)(&hT[0][r * LCW + 4 * k]) = v;
        *(float4*)(&hT[1][r * LCW + 4 * k]) = make_float4(0.f, 0.f, 0.f, 0.f);
    }

    // ---- c state in registers ----
    float cc[8];
    if (has && !zero_init) {
        const float4 a = *(const float4*)(cin + gofs);
        const float4 b = *(const float4*)(cin + gofs + 4);
        cc[0] = a.x; cc[1] = a.y; cc[2] = a.z; cc[3] = a.w;
        cc[4] = b.x; cc[5] = b.y; cc[6] = b.z; cc[7] = b.w;
    } else {
#pragma unroll
        for (int e = 0; e < 8; ++e) cc[e] = 0.f;
    }

    // ---- decoder: hoist constant x-channel conv + bias into registers ----
    v2f xacc[4][4];
    if constexpr (XCONST) {
        if (has) {
#pragma unroll
            for (int co = 0; co < 4; ++co) {
                const v2f bb = {bg[co], bg[co]};
#pragma unroll
                for (int j = 0; j < 4; ++j) xacc[co][j] = bb;
            }
            conv3x8_pk(xbase + gofs - XS, XS, wg, 0, xacc);
        }
    }
    __syncthreads();

    float hh[8];
#pragma unroll
    for (int e = 0; e < 8; ++e) hh[e] = 0.f;

#pragma unroll
    for (int i = 1; i <= NSTEPS; ++i) {
        const float* hR = hT[(i + 1) & 1];   // holds h_{i-1}
        float* hW       = hT[i & 1];         // receives h_i
        const bool act = has && (lr >= i) && (lr < LRN - i);
        if (act) {
            v2f acc[4][4];
            if constexpr (XCONST) {
#pragma unroll
                for (int co = 0; co < 4; ++co)
#pragma unroll
                    for (int j = 0; j < 4; ++j) acc[co][j] = xacc[co][j];
            } else {
#pragma unroll
                for (int co = 0; co < 4; ++co) {
                    const v2f bb = {bg[co], bg[co]};
#pragma unroll
                    for (int j = 0; j < 4; ++j) acc[co][j] = bb;
                }
                conv3x8_pk(xbase + (size_t)(i - 1) * xstep + gofs - XS, XS,
                           wg, 0, acc);
            }
            conv3x8_pk(hR + (lr - 1) * LCW + lc, LCW, wg, 9, acc);
#pragma unroll
            for (int jp = 0; jp < 4; ++jp) {
#pragma unroll
                for (int s = 0; s < 2; ++s) {
                    const int e = 2 * jp + s;
                    const float gi = sigm_(acc[0][jp][s]);
                    const float gf = sigm_(acc[1][jp][s]);
                    const float go = sigm_(acc[2][jp][s]);
                    const float gg = tanh_(acc[3][jp][s]);
                    const float cn = gf * cc[e] + gi * gg;
                    cc[e] = cn;
                    hh[e] = inimg ? (go * tanh_(cn)) : 0.f;  // SAME zero-pad
                }
            }
            *(float4*)(hW + lr * LCW + lc)     = make_float4(hh[0], hh[1], hh[2], hh[3]);
            *(float4*)(hW + lr * LCW + lc + 4) = make_float4(hh[4], hh[5], hh[6], hh[7]);
        }
        __syncthreads();   // h_i visible; next step writes the other buffer
    }

    // ---- interior write-out: rows lr in [8,40), col groups jj in [1,8] ----
    if (has && lr >= 8 && lr < 8 + TROWS && jj >= 1 && jj <= 8) {
        if (dout) {
            const size_t o = (size_t)gr * W + gc0;
            *(float4*)(dout + o)     = make_float4(hh[0], hh[1], hh[2], hh[3]);
            *(float4*)(dout + o + 4) = make_float4(hh[4], hh[5], hh[6], hh[7]);
        } else {
            *(float4*)(hout + gofs)      = make_float4(hh[0], hh[1], hh[2], hh[3]);
            *(float4*)(hout + gofs + 4)  = make_float4(hh[4], hh[5], hh[6], hh[7]);
            *(float4*)(cout_ + gofs)     = make_float4(cc[0], cc[1], cc[2], cc[3]);
            *(float4*)(cout_ + gofs + 4) = make_float4(cc[4], cc[5], cc[6], cc[7]);
        }
    }
}

extern "C" void kernel_launch(void* const* d_in, const int* in_sizes, int n_in,
                              void* d_out, int out_size, void* d_ws, size_t ws_size,
                              hipStream_t stream) {
    const float* data  = (const float*)d_in[0];  // [20,1,1,1024,1024]
    const float* enc_w = (const float*)d_in[1];  // [4,2,3,3]
    const float* enc_b = (const float*)d_in[2];  // [4]
    const float* dec_w = (const float*)d_in[3];
    const float* dec_b = (const float*)d_in[4];
    // d_in[5..7] = epoch(0), T_en(20), T_de(20): constant device scalars;
    // loop counts hardcoded (host can't read device memory under capture).

    float* ws   = (float*)d_ws;
    float* xpad = ws;                 // 20 padded frames
    float* hE0  = ws + 20 * FR;
    float* hE1  = ws + 21 * FR;
    float* cE0  = ws + 22 * FR;
    float* cE1  = ws + 23 * FR;
    float* hX   = ws + 24 * FR;
    float* cX   = ws + 25 * FR;
    float* dout = (float*)d_out;
    // ws use: 26*FR*4 B ~= 114 MB

    init_pad<<<2048, 256, 0, stream>>>(data, ws);

    dim3 blk(NB), grd(512);
    // encoder: steps 0-7, 8-15, 16-19
    fusedN<8, false><<<grd, blk, 0, stream>>>(xpad,           FR, nullptr, nullptr,
                                              hE1, cE1, enc_w, enc_b, nullptr, 1);
    fusedN<8, false><<<grd, blk, 0, stream>>>(xpad +  8 * FR, FR, hE1, cE1,
                                              hE0, cE0, enc_w, enc_b, nullptr, 0);
    fusedN<4, false><<<grd, blk, 0, stream>>>(xpad + 16 * FR, FR, hE0, cE0,
                                              hE1, cE1, enc_w, enc_b, nullptr, 0);
    // final encoder h in hE1 (constant decoder input; zero halo ring = SAME pad)
    fusedN<8, true><<<grd, blk, 0, stream>>>(hE1, 0, nullptr, nullptr,
                                             hE0, cE0, dec_w, dec_b, nullptr, 1);
    fusedN<8, true><<<grd, blk, 0, stream>>>(hE1, 0, hE0, cE0,
                                             hX,  cX,  dec_w, dec_b, nullptr, 0);
    fusedN<4, true><<<grd, blk, 0, stream>>>(hE1, 0, hX,  cX,
                                             nullptr, nullptr, dec_w, dec_b, dout, 0);
}